// Round 1
// baseline (386.702 us; speedup 1.0000x reference)
//
#include <hip/hip_runtime.h>
#include <hip/hip_bf16.h>
#include <stdint.h>

typedef unsigned short u16;
typedef unsigned int   u32;
typedef uint64_t       u64;

using f32x4  = __attribute__((ext_vector_type(4))) float;
using bf16x8 = __attribute__((ext_vector_type(8))) short;

// ---------- helpers ----------
__device__ __forceinline__ u16 f2bf(float f){
  u32 x = __builtin_bit_cast(u32, f);
  x = x + 0x7fffu + ((x >> 16) & 1u);   // RNE
  return (u16)(x >> 16);
}

__device__ __forceinline__ void gload16(const void* g, void* l){
  __builtin_amdgcn_global_load_lds(
      (const __attribute__((address_space(1))) void*)g,
      (__attribute__((address_space(3))) void*)l, 16, 0, 0);
}

__device__ __forceinline__ bf16x8 mkfrag(uint2 h0, uint2 h1){
  union { bf16x8 v; u32 u[4]; } f;
  f.u[0]=h0.x; f.u[1]=h0.y; f.u[2]=h1.x; f.u[3]=h1.y;
  return f.v;
}

// ---------- small converters ----------
__global__ void convx(const float* __restrict__ in, u16* __restrict__ out, int n4){
  for (int i = blockIdx.x*256 + threadIdx.x; i < n4; i += gridDim.x*256){
    float4 v = ((const float4*)in)[i];
    ushort4 o;
    o.x = f2bf(v.x); o.y = f2bf(v.y); o.z = f2bf(v.z); o.w = f2bf(v.w);
    ((ushort4*)out)[i] = o;
  }
}

// in: K x N fp32 (row-major), out: N x K bf16 (transposed)
__global__ __launch_bounds__(256) void wtrans(const float* __restrict__ in,
                                              u16* __restrict__ out, int K, int N){
  __shared__ float tile[32][33];
  const int t = threadIdx.x;
  const int n0 = blockIdx.x*32, k0 = blockIdx.y*32;
  const int r = t >> 3, c4 = (t & 7)*4;
  const float4 v = *(const float4*)(in + (u64)(k0 + r)*N + n0 + c4);
  tile[r][c4+0]=v.x; tile[r][c4+1]=v.y; tile[r][c4+2]=v.z; tile[r][c4+3]=v.w;
  __syncthreads();
  ushort4 o;
  o.x = f2bf(tile[c4+0][r]); o.y = f2bf(tile[c4+1][r]);
  o.z = f2bf(tile[c4+2][r]); o.w = f2bf(tile[c4+3][r]);
  *(ushort4*)(out + (u64)(n0 + r)*K + k0 + c4) = o;
}

// ---------- temperature MLP ----------
__global__ __launch_bounds__(384) void temp_kernel(
    const float* __restrict__ x, const float* __restrict__ w1,
    const float* __restrict__ b1, const float* __restrict__ w2,
    const float* __restrict__ b2, float* __restrict__ lsc){
  const int b = blockIdx.x, t = threadIdx.x;
  __shared__ float cls[768];
  __shared__ float part[6];
  const float* xr = x + (u64)b*577*768;
  cls[t] = xr[t]; cls[t+384] = xr[t+384];
  __syncthreads();
  float h0 = 0.f, h1 = 0.f, h2 = 0.f, h3 = 0.f;
  for (int i = 0; i < 768; i += 4){
    h0 = fmaf(cls[i+0], w1[(u64)(i+0)*384 + t], h0);
    h1 = fmaf(cls[i+1], w1[(u64)(i+1)*384 + t], h1);
    h2 = fmaf(cls[i+2], w1[(u64)(i+2)*384 + t], h2);
    h3 = fmaf(cls[i+3], w1[(u64)(i+3)*384 + t], h3);
  }
  float hacc = fmaxf((h0 + h1) + (h2 + h3) + b1[t], 0.f);
  float v = hacc * w2[t];
  #pragma unroll
  for (int off = 1; off < 64; off <<= 1) v += __shfl_xor(v, off);
  if ((t & 63) == 0) part[t >> 6] = v;
  __syncthreads();
  if (t == 0){
    float s2 = b2[0];
    for (int i = 0; i < 6; i++) s2 += part[i];
    float sig  = 1.f / (1.f + expf(-s2));
    float temp = 0.5f + 2.5f * sig;          // TEMP_MIN + (MAX-MIN)*sigmoid
    lsc[b] = 0.125f / temp;                  // D^-0.5 / temperature
  }
}

// ---------- GEMM: A[M][768] x Bm[N][768]^T ; OUTF=0 -> bf16 out, 1 -> f32+bias ----------
template<int OUTF>
__global__ __launch_bounds__(256, 2) void gemm_nt(
    const u16* __restrict__ A, const u16* __restrict__ Bm,
    void* __restrict__ Cout, const float* __restrict__ bias, int M, int N){
  constexpr int K = 768;
  __shared__ u16 As[128*32];
  __shared__ u16 Bs[128*32];
  const int t = threadIdx.x, l = t & 63, w = t >> 6;
  const int bm = blockIdx.y*128, bn = blockIdx.x*128;
  const int wr = (w >> 1)*64, wc = (w & 1)*64;
  const int g = l >> 4, r16 = l & 15;

  f32x4 acc[4][4];
  #pragma unroll
  for (int i = 0; i < 4; i++)
    #pragma unroll
    for (int j = 0; j < 4; j++) acc[i][j] = (f32x4){0.f,0.f,0.f,0.f};

  const int sr = t >> 2, sc = (t & 3)*8;
  int ar0 = bm + sr;      if (ar0 > M-1) ar0 = M-1;
  int ar1 = bm + sr + 64; if (ar1 > M-1) ar1 = M-1;
  const u16* ga0 = A  + (u64)ar0*K + sc;
  const u16* ga1 = A  + (u64)ar1*K + sc;
  const u16* gb0 = Bm + (u64)(bn + sr)*K + sc;
  const u16* gb1 = Bm + (u64)(bn + sr + 64)*K + sc;
  u16* la0 = As + sr*32 + sc;
  u16* la1 = As + (sr + 64)*32 + sc;
  u16* lb0 = Bs + sr*32 + sc;
  u16* lb1 = Bs + (sr + 64)*32 + sc;

  for (int kt = 0; kt < K; kt += 32){
    gload16(ga0 + kt, la0);
    gload16(ga1 + kt, la1);
    gload16(gb0 + kt, lb0);
    gload16(gb1 + kt, lb1);
    __syncthreads();
    bf16x8 af[4], bfr[4];
    #pragma unroll
    for (int m = 0; m < 4; m++){
      const u16* p = As + (wr + m*16 + r16)*32 + g*4;
      af[m] = mkfrag(*(const uint2*)p, *(const uint2*)(p + 16));
    }
    #pragma unroll
    for (int n = 0; n < 4; n++){
      const u16* p = Bs + (wc + n*16 + r16)*32 + g*4;
      bfr[n] = mkfrag(*(const uint2*)p, *(const uint2*)(p + 16));
    }
    #pragma unroll
    for (int m = 0; m < 4; m++)
      #pragma unroll
      for (int n = 0; n < 4; n++)
        acc[m][n] = __builtin_amdgcn_mfma_f32_16x16x32_bf16(af[m], bfr[n], acc[m][n], 0, 0, 0);
    __syncthreads();
  }
  const int row0 = bm + wr + g*4;
  const int col0 = bn + wc + r16;
  #pragma unroll
  for (int m = 0; m < 4; m++){
    #pragma unroll
    for (int rr = 0; rr < 4; rr++){
      const int row = row0 + m*16 + rr;
      if (row < M){
        #pragma unroll
        for (int n = 0; n < 4; n++){
          const int col = col0 + n*16;
          const float v = acc[m][n][rr];
          if (OUTF) ((float*)Cout)[(u64)row*N + col] = v + bias[col];
          else      ((u16*)Cout)[(u64)row*N + col]  = f2bf(v);
        }
      }
    }
  }
}

// ---------- flash attention ----------
// qkv: [B*577][2304] bf16 (q|k|v each H*64). out: [B*577][768] bf16.
__global__ __launch_bounds__(256, 2) void attn_kernel(
    const u16* __restrict__ qkv, const float* __restrict__ lsc_arr,
    u16* __restrict__ aout){
  const int qt = blockIdx.x, h = blockIdx.y, b = blockIdx.z;
  const int t = threadIdx.x, w = t >> 6, l = t & 63;
  const int g = l >> 4, r16 = l & 15;
  __shared__ u16 Ks[64*64];      // [key][d], 16B-block XOR swizzle key=(row&7)
  __shared__ u16 Vt[64*64];      // [d][key], swizzle key=((d^(d>>3))&7)
  __shared__ u16 Ps[4][16*64];   // per-wave P, swizzle key=(row&7)
  const float lscale = lsc_arr[b];
  const u16* base = qkv + (u64)b*577*2304 + (u64)h*64;

  int qn = qt*64 + w*16 + r16; if (qn > 576) qn = 576;
  bf16x8 qf[2];
  {
    const u16* qr = base + (u64)qn*2304;
    #pragma unroll
    for (int s = 0; s < 2; s++)
      qf[s] = mkfrag(*(const uint2*)(qr + s*32 + g*4),
                     *(const uint2*)(qr + s*32 + g*4 + 16));
  }
  float m_run[4], l_run[4];
  f32x4 oacc[4];
  #pragma unroll
  for (int i = 0; i < 4; i++){ m_run[i] = -1e30f; l_run[i] = 0.f; oacc[i] = (f32x4){0,0,0,0}; }

  u16* Pw = &Ps[w][0];
  const u16* kg = base + 768;
  const u16* vg = base + 1536;

  for (int kt = 0; kt < 10; kt++){
    // stage K tile [64][64] (two passes)
    #pragma unroll
    for (int i = 0; i < 2; i++){
      const int kr = i*32 + (t >> 3);
      int kn = kt*64 + kr; if (kn > 576) kn = 576;
      uint4 kv = *(const uint4*)(kg + (u64)kn*2304 + (t & 7)*8);
      *(uint4*)(Ks + kr*64 + (((t & 7) ^ (kr & 7))*8)) = kv;
    }
    // stage V^T tile [d][key]
    {
      const int kr0 = (t >> 3)*2;
      int kn0 = kt*64 + kr0, kn1 = kn0 + 1;
      if (kn0 > 576) kn0 = 576;
      if (kn1 > 576) kn1 = 576;
      uint4 r0 = *(const uint4*)(vg + (u64)kn0*2304 + (t & 7)*8);
      uint4 r1 = *(const uint4*)(vg + (u64)kn1*2304 + (t & 7)*8);
      const u16* e0 = (const u16*)&r0;
      const u16* e1 = (const u16*)&r1;
      #pragma unroll
      for (int j = 0; j < 8; j++){
        const int d = (t & 7)*8 + j;
        const int key = (d ^ (d >> 3)) & 7;
        const u32 val = (u32)e0[j] | ((u32)e1[j] << 16);
        *(u32*)(Vt + d*64 + (((kr0 >> 3) ^ key)*8) + (kr0 & 7)) = val;
      }
    }
    __syncthreads();

    // S = Q K^T  (per wave: 16 q-rows x 64 keys)
    f32x4 sacc[4];
    #pragma unroll
    for (int i = 0; i < 4; i++) sacc[i] = (f32x4){0,0,0,0};
    #pragma unroll
    for (int fn = 0; fn < 4; fn++){
      const int kr = fn*16 + r16;
      const int kk = kr & 7;
      const u16* rowp = Ks + kr*64 + (g & 1)*4;
      #pragma unroll
      for (int s = 0; s < 2; s++){
        const int b0 = (4*s + (g >> 1)) ^ kk;
        sacc[fn] = __builtin_amdgcn_mfma_f32_16x16x32_bf16(
            qf[s],
            mkfrag(*(const uint2*)(rowp + b0*8), *(const uint2*)(rowp + (b0 ^ 2)*8)),
            sacc[fn], 0, 0, 0);
      }
    }
    // scale + mask
    const int colb = kt*64 + r16;
    #pragma unroll
    for (int fn = 0; fn < 4; fn++){
      const bool valid = (colb + fn*16) <= 576;
      #pragma unroll
      for (int rr = 0; rr < 4; rr++){
        const float v = sacc[fn][rr]*lscale;
        sacc[fn][rr] = valid ? v : -1e30f;
      }
    }
    // online softmax (rows live in 16-lane groups)
    float mx[4];
    #pragma unroll
    for (int rr = 0; rr < 4; rr++)
      mx[rr] = fmaxf(fmaxf(sacc[0][rr], sacc[1][rr]), fmaxf(sacc[2][rr], sacc[3][rr]));
    #pragma unroll
    for (int off = 1; off < 16; off <<= 1)
      #pragma unroll
      for (int rr = 0; rr < 4; rr++)
        mx[rr] = fmaxf(mx[rr], __shfl_xor(mx[rr], off));
    float corr[4];
    #pragma unroll
    for (int rr = 0; rr < 4; rr++){
      const float nm = fmaxf(m_run[rr], mx[rr]);
      corr[rr] = __expf(m_run[rr] - nm);
      m_run[rr] = nm;
    }
    float rs[4] = {0.f, 0.f, 0.f, 0.f};
    u16 pb[4][4];
    #pragma unroll
    for (int fn = 0; fn < 4; fn++)
      #pragma unroll
      for (int rr = 0; rr < 4; rr++){
        const float p = __expf(sacc[fn][rr] - m_run[rr]);
        rs[rr] += p;
        pb[fn][rr] = f2bf(p);
      }
    #pragma unroll
    for (int off = 1; off < 16; off <<= 1)
      #pragma unroll
      for (int rr = 0; rr < 4; rr++)
        rs[rr] += __shfl_xor(rs[rr], off);
    #pragma unroll
    for (int rr = 0; rr < 4; rr++) l_run[rr] = l_run[rr]*corr[rr] + rs[rr];
    #pragma unroll
    for (int df = 0; df < 4; df++)
      #pragma unroll
      for (int rr = 0; rr < 4; rr++)
        oacc[df][rr] *= corr[rr];
    // P -> LDS (D-layout write, A-layout read)
    #pragma unroll
    for (int fn = 0; fn < 4; fn++){
      const int pcol = fn*16 + r16;
      #pragma unroll
      for (int rr = 0; rr < 4; rr++){
        const int prow = g*4 + rr;
        Pw[prow*64 + (((pcol >> 3) ^ (prow & 7))*8) + (pcol & 7)] = pb[fn][rr];
      }
    }
    // O += P V
    #pragma unroll
    for (int s = 0; s < 2; s++){
      const int pk = r16 & 7;
      const u16* prp = Pw + r16*64 + (g & 1)*4;
      const int b0 = (4*s + (g >> 1)) ^ pk;
      const bf16x8 pa = mkfrag(*(const uint2*)(prp + b0*8),
                               *(const uint2*)(prp + (b0 ^ 2)*8));
      #pragma unroll
      for (int df = 0; df < 4; df++){
        const int vd = df*16 + r16;
        const int vk = (vd ^ (vd >> 3)) & 7;
        const u16* vrp = Vt + vd*64 + (g & 1)*4;
        const int c0 = (4*s + (g >> 1)) ^ vk;
        const bf16x8 vf = mkfrag(*(const uint2*)(vrp + c0*8),
                                 *(const uint2*)(vrp + (c0 ^ 2)*8));
        oacc[df] = __builtin_amdgcn_mfma_f32_16x16x32_bf16(pa, vf, oacc[df], 0, 0, 0);
      }
    }
    __syncthreads();
  }
  // epilogue: O/l -> bf16 [row][h*64+d]
  #pragma unroll
  for (int df = 0; df < 4; df++){
    const int d = df*16 + r16;
    #pragma unroll
    for (int rr = 0; rr < 4; rr++){
      const int n = qt*64 + w*16 + g*4 + rr;
      if (n <= 576){
        const float v = oacc[df][rr] / l_run[rr];
        aout[(u64)(b*577 + n)*768 + h*64 + d] = f2bf(v);
      }
    }
  }
}

// ---------- launcher ----------
extern "C" void kernel_launch(void* const* d_in, const int* in_sizes, int n_in,
                              void* d_out, int out_size, void* d_ws, size_t ws_size,
                              hipStream_t stream){
  const float* x      = (const float*)d_in[0];
  const float* qkv_w  = (const float*)d_in[1];
  const float* proj_w = (const float*)d_in[2];
  const float* proj_b = (const float*)d_in[3];
  const float* t_w1   = (const float*)d_in[4];
  const float* t_b1   = (const float*)d_in[5];
  const float* t_w2   = (const float*)d_in[6];
  const float* t_b2   = (const float*)d_in[7];

  // ws layout (256B-aligned regions), total 75,620,608 bytes
  const u64 off_xb  = 256;
  const u64 off_qwT = off_xb  + 14180352ull;  // x bf16      [9232][768]
  const u64 off_pwT = off_qwT + 3538944ull;   // qkv_w^T     [2304][768]
  const u64 off_qkv = off_pwT + 1179648ull;   // proj_w^T    [768][768]
  const u64 off_ao  = off_qkv + 42541056ull;  // qkv bf16    [9232][2304]
  const u64 need    = off_ao  + 14180352ull;  // attn out    [9232][768]
  if (ws_size < need) return;  // visible-failure guard: output stays poisoned

  char* ws  = (char*)d_ws;
  float* lsc = (float*)ws;
  u16* xb   = (u16*)(ws + off_xb);
  u16* qwT  = (u16*)(ws + off_qwT);
  u16* pwT  = (u16*)(ws + off_pwT);
  u16* qkv  = (u16*)(ws + off_qkv);
  u16* ao   = (u16*)(ws + off_ao);

  convx<<<1024, 256, 0, stream>>>(x, xb, (16*577*768)/4);
  wtrans<<<dim3(2304/32, 768/32), 256, 0, stream>>>(qkv_w, qwT, 768, 2304);
  wtrans<<<dim3(768/32, 768/32), 256, 0, stream>>>(proj_w, pwT, 768, 768);
  temp_kernel<<<16, 384, 0, stream>>>(x, t_w1, t_b1, t_w2, t_b2, lsc);
  gemm_nt<0><<<dim3(2304/128, 73), 256, 0, stream>>>(xb, qwT, qkv, nullptr, 9232, 2304);
  attn_kernel<<<dim3(10, 12, 16), 256, 0, stream>>>(qkv, lsc, ao);
  gemm_nt<1><<<dim3(768/128, 73), 256, 0, stream>>>(ao, pwT, d_out, proj_b, 9232, 768);
}

// Round 3
// 253.296 us; speedup vs baseline: 1.5267x; 1.5267x over previous
//
#include <hip/hip_runtime.h>
#include <hip/hip_bf16.h>
#include <stdint.h>

typedef unsigned short u16;
typedef unsigned int   u32;
typedef uint64_t       u64;

using f32x4  = __attribute__((ext_vector_type(4))) float;
using bf16x8 = __attribute__((ext_vector_type(8))) short;

// ---------- helpers ----------
__device__ __forceinline__ u16 f2bf(float f){
  u32 x = __builtin_bit_cast(u32, f);
  x = x + 0x7fffu + ((x >> 16) & 1u);   // RNE
  return (u16)(x >> 16);
}

__device__ __forceinline__ void gload16(const void* g, void* l){
  __builtin_amdgcn_global_load_lds(
      (const __attribute__((address_space(1))) void*)g,
      (__attribute__((address_space(3))) void*)l, 16, 0, 0);
}

__device__ __forceinline__ bf16x8 mkfrag(uint2 h0, uint2 h1){
  union { bf16x8 v; u32 u[4]; } f;
  f.u[0]=h0.x; f.u[1]=h0.y; f.u[2]=h1.x; f.u[3]=h1.y;
  return f.v;
}

// ---------- small converters ----------
__global__ void convx(const float* __restrict__ in, u16* __restrict__ out, int n4){
  for (int i = blockIdx.x*256 + threadIdx.x; i < n4; i += gridDim.x*256){
    float4 v = ((const float4*)in)[i];
    ushort4 o;
    o.x = f2bf(v.x); o.y = f2bf(v.y); o.z = f2bf(v.z); o.w = f2bf(v.w);
    ((ushort4*)out)[i] = o;
  }
}

// in: K x N fp32 (row-major), out: N x K bf16 (transposed)
__global__ __launch_bounds__(256) void wtrans(const float* __restrict__ in,
                                              u16* __restrict__ out, int K, int N){
  __shared__ float tile[32][33];
  const int t = threadIdx.x;
  const int n0 = blockIdx.x*32, k0 = blockIdx.y*32;
  const int r = t >> 3, c4 = (t & 7)*4;
  const float4 v = *(const float4*)(in + (u64)(k0 + r)*N + n0 + c4);
  tile[r][c4+0]=v.x; tile[r][c4+1]=v.y; tile[r][c4+2]=v.z; tile[r][c4+3]=v.w;
  __syncthreads();
  ushort4 o;
  o.x = f2bf(tile[c4+0][r]); o.y = f2bf(tile[c4+1][r]);
  o.z = f2bf(tile[c4+2][r]); o.w = f2bf(tile[c4+3][r]);
  *(ushort4*)(out + (u64)(n0 + r)*K + k0 + c4) = o;
}

// ---------- temperature MLP ----------
__global__ __launch_bounds__(384) void temp_kernel(
    const float* __restrict__ x, const float* __restrict__ w1,
    const float* __restrict__ b1, const float* __restrict__ w2,
    const float* __restrict__ b2, float* __restrict__ lsc){
  const int b = blockIdx.x, t = threadIdx.x;
  __shared__ float cls[768];
  __shared__ float part[6];
  const float* xr = x + (u64)b*577*768;
  cls[t] = xr[t]; cls[t+384] = xr[t+384];
  __syncthreads();
  float h0 = 0.f, h1 = 0.f, h2 = 0.f, h3 = 0.f;
  for (int i = 0; i < 768; i += 4){
    h0 = fmaf(cls[i+0], w1[(u64)(i+0)*384 + t], h0);
    h1 = fmaf(cls[i+1], w1[(u64)(i+1)*384 + t], h1);
    h2 = fmaf(cls[i+2], w1[(u64)(i+2)*384 + t], h2);
    h3 = fmaf(cls[i+3], w1[(u64)(i+3)*384 + t], h3);
  }
  float hacc = fmaxf((h0 + h1) + (h2 + h3) + b1[t], 0.f);
  float v = hacc * w2[t];
  #pragma unroll
  for (int off = 1; off < 64; off <<= 1) v += __shfl_xor(v, off);
  if ((t & 63) == 0) part[t >> 6] = v;
  __syncthreads();
  if (t == 0){
    float s2 = b2[0];
    for (int i = 0; i < 6; i++) s2 += part[i];
    float sig  = 1.f / (1.f + expf(-s2));
    float temp = 0.5f + 2.5f * sig;          // TEMP_MIN + (MAX-MIN)*sigmoid
    lsc[b] = 0.125f / temp;                  // D^-0.5 / temperature
  }
}

// ---------- GEMM: A[M][768] x Bm[N][768]^T ; OUTF=0 -> bf16 out, 1 -> f32+bias ----------
// BK=64, LDS tiles [128][64] u16 with 16B-unit XOR swizzle: unit' = unit ^ (row&7).
// Staged with global_load_lds (linear LDS dest) + pre-swizzled per-lane GLOBAL source.
template<int OUTF>
__global__ __launch_bounds__(256, 2) void gemm_nt(
    const u16* __restrict__ A, const u16* __restrict__ Bm,
    void* __restrict__ Cout, const float* __restrict__ bias, int M, int N){
  constexpr int K = 768;
  __shared__ u16 As[128*64];
  __shared__ u16 Bs[128*64];
  const int t = threadIdx.x, l = t & 63, w = t >> 6;
  const int bm = blockIdx.y*128, bn = blockIdx.x*128;
  const int wr = (w >> 1)*64, wc = (w & 1)*64;
  const int g = l >> 4, r16 = l & 15;

  f32x4 acc[4][4];
  #pragma unroll
  for (int i = 0; i < 4; i++)
    #pragma unroll
    for (int j = 0; j < 4; j++) acc[i][j] = (f32x4){0.f,0.f,0.f,0.f};

  // staging geometry: issue i covers tile rows [i*32, i*32+32).
  // thread t -> tile row i*32 + (t>>3), LDS 16B-unit position (t&7).
  // data for swizzled position p is global unit u = p ^ (row&7).
  const int srow = t >> 3;                  // 0..31
  const int su   = (t & 7) ^ (srow & 7);    // source 16B-unit within the 64-k slab
  const u16* gA[4]; const u16* gB[4];
  #pragma unroll
  for (int i = 0; i < 4; i++){
    int ra = bm + i*32 + srow; if (ra > M-1) ra = M-1;
    gA[i] = A  + (u64)ra*K + su*8;
    gB[i] = Bm + (u64)(bn + i*32 + srow)*K + su*8;
  }
  u16* lA = As + t*8;
  u16* lB = Bs + t*8;

  for (int kt = 0; kt < K; kt += 64){
    #pragma unroll
    for (int i = 0; i < 4; i++) gload16(gA[i] + kt, lA + i*2048);
    #pragma unroll
    for (int i = 0; i < 4; i++) gload16(gB[i] + kt, lB + i*2048);
    __syncthreads();
    #pragma unroll
    for (int s = 0; s < 2; s++){
      const int c   = s*4 + (g >> 1);       // global 16B-unit of this k-chunk
      const int off = (g & 1)*4;            // u16 offset within unit
      bf16x8 af[4], bfr[4];
      #pragma unroll
      for (int m = 0; m < 4; m++){
        const int R = wr + m*16 + r16;
        const int i1 = R*64 + ((c ^ (R & 7))*8) + off;
        af[m] = mkfrag(*(const uint2*)(As + i1), *(const uint2*)(As + (i1 ^ 16)));
      }
      #pragma unroll
      for (int n = 0; n < 4; n++){
        const int R = wc + n*16 + r16;
        const int i1 = R*64 + ((c ^ (R & 7))*8) + off;
        bfr[n] = mkfrag(*(const uint2*)(Bs + i1), *(const uint2*)(Bs + (i1 ^ 16)));
      }
      #pragma unroll
      for (int m = 0; m < 4; m++)
        #pragma unroll
        for (int n = 0; n < 4; n++)
          acc[m][n] = __builtin_amdgcn_mfma_f32_16x16x32_bf16(af[m], bfr[n], acc[m][n], 0, 0, 0);
    }
    __syncthreads();
  }
  const int row0 = bm + wr + g*4;
  const int col0 = bn + wc + r16;
  #pragma unroll
  for (int m = 0; m < 4; m++){
    #pragma unroll
    for (int rr = 0; rr < 4; rr++){
      const int row = row0 + m*16 + rr;
      if (row < M){
        #pragma unroll
        for (int n = 0; n < 4; n++){
          const int col = col0 + n*16;
          const float v = acc[m][n][rr];
          if (OUTF) ((float*)Cout)[(u64)row*N + col] = v + bias[col];
          else      ((u16*)Cout)[(u64)row*N + col]  = f2bf(v);
        }
      }
    }
  }
}

// ---------- flash attention ----------
// qkv: [B*577][2304] bf16 (q|k|v each H*64). out: [B*577][768] bf16.
// S^T trick: compute mfma(K,Q) so each lane holds P-values of ONE q-row whose
// k-layout matches the PV A-fragment exactly -> P stays in registers.
__global__ __launch_bounds__(256, 2) void attn_kernel(
    const u16* __restrict__ qkv, const float* __restrict__ lsc_arr,
    u16* __restrict__ aout){
  const int qt = blockIdx.x, h = blockIdx.y, b = blockIdx.z;
  const int t = threadIdx.x, w = t >> 6, l = t & 63;
  const int g = l >> 4, r16 = l & 15;
  __shared__ u16 Ks[64*64];      // [key][d], 16B-unit XOR swizzle key=(row&7)
  __shared__ u16 Vt[64*64];      // [d][key], swizzle key=((d^(d>>3))&7)
  const float lscale = lsc_arr[b];
  const u16* base = qkv + (u64)b*577*2304 + (u64)h*64;

  int qn = qt*64 + w*16 + r16; if (qn > 576) qn = 576;
  bf16x8 qf[2];
  {
    const u16* qr = base + (u64)qn*2304;
    #pragma unroll
    for (int s = 0; s < 2; s++)
      qf[s] = mkfrag(*(const uint2*)(qr + s*32 + g*4),
                     *(const uint2*)(qr + s*32 + g*4 + 16));
  }
  float m_run = -1e30f, l_run = 0.f;
  f32x4 oacc[4];
  #pragma unroll
  for (int i = 0; i < 4; i++) oacc[i] = (f32x4){0,0,0,0};

  const u16* kg = base + 768;
  const u16* vg = base + 1536;
  const int srcb = (l & 48) | (((l >> 4) & 3)*4);   // lane holding q-row 4g+rr at +rr

  for (int kt = 0; kt < 10; kt++){
    // stage K tile [64][64] (two passes)
    #pragma unroll
    for (int i = 0; i < 2; i++){
      const int kr = i*32 + (t >> 3);
      int kn = kt*64 + kr; if (kn > 576) kn = 576;
      uint4 kv = *(const uint4*)(kg + (u64)kn*2304 + (t & 7)*8);
      *(uint4*)(Ks + kr*64 + (((t & 7) ^ (kr & 7))*8)) = kv;
    }
    // stage V^T tile [d][key]
    {
      const int kr0 = (t >> 3)*2;
      int kn0 = kt*64 + kr0, kn1 = kn0 + 1;
      if (kn0 > 576) kn0 = 576;
      if (kn1 > 576) kn1 = 576;
      uint4 r0 = *(const uint4*)(vg + (u64)kn0*2304 + (t & 7)*8);
      uint4 r1 = *(const uint4*)(vg + (u64)kn1*2304 + (t & 7)*8);
      const u16* e0 = (const u16*)&r0;
      const u16* e1 = (const u16*)&r1;
      #pragma unroll
      for (int j = 0; j < 8; j++){
        const int d = (t & 7)*8 + j;
        const int key = (d ^ (d >> 3)) & 7;
        const u32 val = (u32)e0[j] | ((u32)e1[j] << 16);
        *(u32*)(Vt + d*64 + (((kr0 >> 3) ^ key)*8) + (kr0 & 7)) = val;
      }
    }
    __syncthreads();

    // S^T = K Q^T  (per wave: 64 keys x 16 q-rows; lane holds keys fn*16+4g+rr for q=r16)
    f32x4 sacc[4];
    #pragma unroll
    for (int i = 0; i < 4; i++) sacc[i] = (f32x4){0,0,0,0};
    #pragma unroll
    for (int fn = 0; fn < 4; fn++){
      const int kr = fn*16 + r16;
      const int kk = kr & 7;
      const u16* rowp = Ks + kr*64 + (g & 1)*4;
      #pragma unroll
      for (int s = 0; s < 2; s++){
        const int b0 = (4*s + (g >> 1)) ^ kk;
        sacc[fn] = __builtin_amdgcn_mfma_f32_16x16x32_bf16(
            mkfrag(*(const uint2*)(rowp + b0*8), *(const uint2*)(rowp + (b0 ^ 2)*8)),
            qf[s], sacc[fn], 0, 0, 0);
      }
    }
    // scale + mask (rows = keys now)
    #pragma unroll
    for (int fn = 0; fn < 4; fn++)
      #pragma unroll
      for (int rr = 0; rr < 4; rr++){
        const bool valid = (kt*64 + fn*16 + g*4 + rr) <= 576;
        const float v = sacc[fn][rr]*lscale;
        sacc[fn][rr] = valid ? v : -1e30f;
      }
    // online softmax: all 16 values on a lane belong to q-row r16
    float mx = sacc[0][0];
    #pragma unroll
    for (int fn = 0; fn < 4; fn++)
      #pragma unroll
      for (int rr = 0; rr < 4; rr++) mx = fmaxf(mx, sacc[fn][rr]);
    mx = fmaxf(mx, __shfl_xor(mx, 16));
    mx = fmaxf(mx, __shfl_xor(mx, 32));
    const float nm = fmaxf(m_run, mx);
    const float corr = __expf(m_run - nm);
    m_run = nm;
    float rs = 0.f;
    u16 pb[4][4];
    #pragma unroll
    for (int fn = 0; fn < 4; fn++)
      #pragma unroll
      for (int rr = 0; rr < 4; rr++){
        const float p = __expf(sacc[fn][rr] - m_run);
        rs += p;
        pb[fn][rr] = f2bf(p);
      }
    rs += __shfl_xor(rs, 16);
    rs += __shfl_xor(rs, 32);
    l_run = l_run*corr + rs;
    // rescale O rows (lane's O rows are q = 4g+rr, not r16 -> broadcast corr)
    float corrO[4];
    #pragma unroll
    for (int rr = 0; rr < 4; rr++) corrO[rr] = __shfl(corr, srcb + rr);
    #pragma unroll
    for (int df = 0; df < 4; df++)
      #pragma unroll
      for (int rr = 0; rr < 4; rr++)
        oacc[df][rr] *= corrO[rr];
    // O += P V  (P fragments straight from registers)
    #pragma unroll
    for (int s = 0; s < 2; s++){
      union { bf16x8 v; u32 u[4]; } pa;
      pa.u[0] = (u32)pb[2*s][0]   | ((u32)pb[2*s][1]   << 16);
      pa.u[1] = (u32)pb[2*s][2]   | ((u32)pb[2*s][3]   << 16);
      pa.u[2] = (u32)pb[2*s+1][0] | ((u32)pb[2*s+1][1] << 16);
      pa.u[3] = (u32)pb[2*s+1][2] | ((u32)pb[2*s+1][3] << 16);
      #pragma unroll
      for (int df = 0; df < 4; df++){
        const int vd = df*16 + r16;
        const int vk = (vd ^ (vd >> 3)) & 7;
        const u16* vrp = Vt + vd*64 + (g & 1)*4;
        const int c0 = (4*s + (g >> 1)) ^ vk;
        const bf16x8 vf = mkfrag(*(const uint2*)(vrp + c0*8),
                                 *(const uint2*)(vrp + (c0 ^ 2)*8));
        oacc[df] = __builtin_amdgcn_mfma_f32_16x16x32_bf16(pa.v, vf, oacc[df], 0, 0, 0);
      }
    }
    __syncthreads();
  }
  // epilogue: O/l -> bf16 [row][h*64+d]
  float lO[4];
  #pragma unroll
  for (int rr = 0; rr < 4; rr++) lO[rr] = __shfl(l_run, srcb + rr);
  #pragma unroll
  for (int df = 0; df < 4; df++){
    const int d = df*16 + r16;
    #pragma unroll
    for (int rr = 0; rr < 4; rr++){
      const int n = qt*64 + w*16 + g*4 + rr;
      if (n <= 576){
        const float v = oacc[df][rr] / lO[rr];
        aout[(u64)(b*577 + n)*768 + h*64 + d] = f2bf(v);
      }
    }
  }
}

// ---------- launcher ----------
extern "C" void kernel_launch(void* const* d_in, const int* in_sizes, int n_in,
                              void* d_out, int out_size, void* d_ws, size_t ws_size,
                              hipStream_t stream){
  const float* x      = (const float*)d_in[0];
  const float* qkv_w  = (const float*)d_in[1];
  const float* proj_w = (const float*)d_in[2];
  const float* proj_b = (const float*)d_in[3];
  const float* t_w1   = (const float*)d_in[4];
  const float* t_b1   = (const float*)d_in[5];
  const float* t_w2   = (const float*)d_in[6];
  const float* t_b2   = (const float*)d_in[7];

  // ws layout (256B-aligned regions), total 75,620,608 bytes
  const u64 off_xb  = 256;
  const u64 off_qwT = off_xb  + 14180352ull;  // x bf16      [9232][768]
  const u64 off_pwT = off_qwT + 3538944ull;   // qkv_w^T     [2304][768]
  const u64 off_qkv = off_pwT + 1179648ull;   // proj_w^T    [768][768]
  const u64 off_ao  = off_qkv + 42541056ull;  // qkv bf16    [9232][2304]
  const u64 need    = off_ao  + 14180352ull;  // attn out    [9232][768]
  if (ws_size < need) return;  // visible-failure guard: output stays poisoned

  char* ws  = (char*)d_ws;
  float* lsc = (float*)ws;
  u16* xb   = (u16*)(ws + off_xb);
  u16* qwT  = (u16*)(ws + off_qwT);
  u16* pwT  = (u16*)(ws + off_pwT);
  u16* qkv  = (u16*)(ws + off_qkv);
  u16* ao   = (u16*)(ws + off_ao);

  convx<<<1024, 256, 0, stream>>>(x, xb, (16*577*768)/4);
  wtrans<<<dim3(2304/32, 768/32), 256, 0, stream>>>(qkv_w, qwT, 768, 2304);
  wtrans<<<dim3(768/32, 768/32), 256, 0, stream>>>(proj_w, pwT, 768, 768);
  temp_kernel<<<16, 384, 0, stream>>>(x, t_w1, t_b1, t_w2, t_b2, lsc);
  gemm_nt<0><<<dim3(2304/128, 73), 256, 0, stream>>>(xb, qwT, qkv, nullptr, 9232, 2304);
  attn_kernel<<<dim3(10, 12, 16), 256, 0, stream>>>(qkv, lsc, ao);
  gemm_nt<1><<<dim3(768/128, 73), 256, 0, stream>>>(ao, pwT, d_out, proj_b, 9232, 768);
}